// Round 6
// baseline (4725.698 us; speedup 1.0000x reference)
//
#include <hip/hip_runtime.h>
#include <stdint.h>

// Problem constants (reference: B=2, S=2048, E=2048, H=16, D=128)
constexpr int BATCH = 2;
constexpr int SEQ   = 2048;
constexpr int EMB   = 2048;
constexpr int NH    = 16;
constexpr int HD    = 128;

typedef unsigned short u16;
typedef __attribute__((ext_vector_type(8))) short bf16x8;
typedef __attribute__((ext_vector_type(4))) float floatx4;

__device__ inline float bf2f(u16 u) {
  union { unsigned int i; float f; } v; v.i = ((unsigned int)u) << 16; return v.f;
}
__device__ inline u16 f2bf(float f) {
  union { float f; unsigned int i; } v; v.f = f;
  unsigned int x = v.i;
  return (u16)((x + 0x7fffu + ((x >> 16) & 1u)) >> 16);  // RNE
}

__device__ inline void load_lds16(const void* g, void* l) {
  __builtin_amdgcn_global_load_lds((const __attribute__((address_space(1))) unsigned int*)g,
                                   (__attribute__((address_space(3))) unsigned int*)l,
                                   16, 0, 0);
}

// ---------------------------------------------------------------------------
// fp32 -> bf16 elementwise convert (vectorized x4)
// ---------------------------------------------------------------------------
__global__ void cvt_f32_bf16(const float* __restrict__ src, u16* __restrict__ dst, int n4) {
  const int i = blockIdx.x * blockDim.x + threadIdx.x;
  if (i < n4) {
    const float4 v = ((const float4*)src)[i];
    ushort4 o;
    o.x = f2bf(v.x); o.y = f2bf(v.y); o.z = f2bf(v.z); o.w = f2bf(v.w);
    ((ushort4*)dst)[i] = o;
  }
}

// ---------------------------------------------------------------------------
// C[M,N] = A[M,K] @ B[N,K]^T   (bf16 in, fp32 accumulate) — m97 pattern
// F32OUT: store fp32 to Cf, else bf16 to Cb.
// block = 256 threads (4 waves, 2x2 over 128x128 C-tile), BK=32
// ---------------------------------------------------------------------------
constexpr int BM = 128, BN = 128, BK = 32;

template <bool F32OUT>
__global__ __launch_bounds__(256) void gemm_bt(const u16* __restrict__ A,
                                               const u16* __restrict__ Bm,
                                               u16* __restrict__ Cb,
                                               float* __restrict__ Cf,
                                               int M, int N, int K) {
  __shared__ __align__(16) u16 As[BM * BK];
  __shared__ __align__(16) u16 Bs[BN * BK];
  const int tid  = threadIdx.x;
  const int wave = tid >> 6, lane = tid & 63;
  const int wm = (wave & 1) * 64, wn = (wave >> 1) * 64;
  const int m0 = blockIdx.y * BM, n0 = blockIdx.x * BN;

  floatx4 acc[4][4];
#pragma unroll
  for (int i = 0; i < 4; ++i)
#pragma unroll
    for (int j = 0; j < 4; ++j) acc[i][j] = {0.f, 0.f, 0.f, 0.f};

  const int lrow = lane >> 2;       // 0..15 (staging row within 16-row chunk)
  const int lcol = (lane & 3) * 8;  // staging col (8 bf16 = 16 B)
  const int frow = lane & 15;       // fragment row
  const int fk   = (lane >> 4) * 8; // fragment k offset

  for (int kt = 0; kt < K; kt += BK) {
#pragma unroll
    for (int inst = 0; inst < 2; ++inst) {
      const int rbase = wave * 32 + inst * 16;  // wave-uniform
      load_lds16(A  + (size_t)(m0 + rbase + lrow) * K + kt + lcol, &As[rbase * BK]);
      load_lds16(Bm + (size_t)(n0 + rbase + lrow) * K + kt + lcol, &Bs[rbase * BK]);
    }
    asm volatile("s_waitcnt vmcnt(0)" ::: "memory");
    __syncthreads();

    bf16x8 af[4], bfr[4];
#pragma unroll
    for (int mi = 0; mi < 4; ++mi)
      af[mi] = *(const bf16x8*)&As[(wm + mi * 16 + frow) * BK + fk];
#pragma unroll
    for (int ni = 0; ni < 4; ++ni)
      bfr[ni] = *(const bf16x8*)&Bs[(wn + ni * 16 + frow) * BK + fk];
#pragma unroll
    for (int mi = 0; mi < 4; ++mi)
#pragma unroll
      for (int ni = 0; ni < 4; ++ni)
        acc[mi][ni] = __builtin_amdgcn_mfma_f32_16x16x32_bf16(af[mi], bfr[ni], acc[mi][ni], 0, 0, 0);
    __syncthreads();
  }

  // C/D layout: col = lane&15, row = (lane>>4)*4 + r
  const int crow0 = (lane >> 4) * 4;
  const int ccol  = lane & 15;
#pragma unroll
  for (int mi = 0; mi < 4; ++mi)
#pragma unroll
    for (int ni = 0; ni < 4; ++ni) {
      const int row = m0 + wm + mi * 16 + crow0;
      const int col = n0 + wn + ni * 16 + ccol;
#pragma unroll
      for (int r = 0; r < 4; ++r) {
        const size_t off = (size_t)(row + r) * N + col;
        if (F32OUT) Cf[off] = acc[mi][ni][r];
        else        Cb[off] = f2bf(acc[mi][ni][r]);
      }
    }
}

// ---------------------------------------------------------------------------
// In-place RoPE on qkv[B,S,3,NH,HD]: rotates Q and K thirds, V untouched.
// one thread per (b,s,h, j<64); handles d=j and d=j+64
// ---------------------------------------------------------------------------
__global__ void rope_inplace(u16* __restrict__ qkv) {
  const int t   = blockIdx.x * blockDim.x + threadIdx.x;
  const int j   = t & 63;
  const int idx = t >> 6;            // bs*NH + h
  const int h   = idx & (NH - 1);
  const int bs  = idx >> 4;          // b*SEQ + s
  const int s   = bs & (SEQ - 1);

  u16* base = qkv + (size_t)bs * (3 * EMB) + h * HD;

  const float inv_freq = exp2f(-(float)j * (13.287712379549449f / 64.0f)); // 10000^(-j/64)
  const float ang = (float)s * inv_freq;
  const float c = cosf(ang), sn = sinf(ang);

#pragma unroll
  for (int part = 0; part < 2; ++part) {   // part 0 = Q, part 1 = K
    u16* p = base + part * EMB;
    const float x1 = bf2f(p[j]), x2 = bf2f(p[j + 64]);
    p[j]      = f2bf(x1 * c - x2 * sn);
    p[j + 64] = f2bf(x2 * c + x1 * sn);
  }
}

// ---------------------------------------------------------------------------
// Scalar flash attention (online softmax), causal. Reads q/k/v directly from
// the rope'd qkv buffer (row stride 3E). Y output layout [B,S,E] bf16.
// block = 256 threads = 4 waves; 64 queries/block (16/wave); key tiles of 64.
// ---------------------------------------------------------------------------
constexpr int QB = 64, KTILE = 64;
constexpr int QKV_STRIDE = 3 * EMB;   // row stride in the qkv buffer

__global__ __launch_bounds__(256) void attn_flash(const u16* __restrict__ qkv,
                                                  u16* __restrict__ Y) {
  __shared__ __align__(16) u16 q_sh[QB][HD];       // 16 KB
  __shared__ __align__(16) u16 k_sh[HD][KTILE];    // 16 KB (transposed)
  __shared__ __align__(16) u16 v_sh[KTILE][HD];    // 16 KB

  const int tid  = threadIdx.x;
  const int wave = tid >> 6, lane = tid & 63;
  const int bh = blockIdx.y;                       // b*NH + h
  const int q0 = blockIdx.x * QB;
  const int b = bh >> 4, h = bh & 15;

  // row s of head h: Qp + s*QKV_STRIDE  (K at +EMB, V at +2*EMB)
  const u16* Qp = qkv + (size_t)b * SEQ * QKV_STRIDE + h * HD;
  const u16* Kp = Qp + EMB;
  const u16* Vp = Qp + 2 * EMB;

  { // load q tile (64 rows x 128): 4 threads/row, 64 B each
    const int r = tid >> 2, cp = (tid & 3) * 32;
    const uint4* srcp = (const uint4*)(Qp + (size_t)(q0 + r) * QKV_STRIDE + cp);
    uint4* dstp = (uint4*)&q_sh[r][cp];
    dstp[0] = srcp[0]; dstp[1] = srcp[1]; dstp[2] = srcp[2]; dstp[3] = srcp[3];
  }

  float m_i[16], l_i[16], o0[16], o1[16];
#pragma unroll
  for (int i = 0; i < 16; ++i) { m_i[i] = -INFINITY; l_i[i] = 0.f; o0[i] = 0.f; o1[i] = 0.f; }

  const int qbase = q0 + wave * 16;
  const int ntiles = q0 / KTILE + 1;               // causal: keys 0..q0+63
  const float scale = 0.08838834764831845f;        // 1/sqrt(128)

  for (int t = 0; t < ntiles; ++t) {
    __syncthreads();  // protect LDS from previous tile's readers (and q_sh load)
    { // stage K (transposed) + V tiles
      const int kk = tid >> 2, cp = (tid & 3) * 32;
      const uint4* ks = (const uint4*)(Kp + (size_t)(t * KTILE + kk) * QKV_STRIDE + cp);
      uint4 kr[4] = {ks[0], ks[1], ks[2], ks[3]};
      const uint4* vs = (const uint4*)(Vp + (size_t)(t * KTILE + kk) * QKV_STRIDE + cp);
      uint4 vr[4] = {vs[0], vs[1], vs[2], vs[3]};
      uint4* vd = (uint4*)&v_sh[kk][cp];
      vd[0] = vr[0]; vd[1] = vr[1]; vd[2] = vr[2]; vd[3] = vr[3];
      const u16* krs = (const u16*)kr;
#pragma unroll
      for (int i = 0; i < 32; ++i) k_sh[cp + i][kk] = krs[i];
    }
    __syncthreads();

    for (int qi = 0; qi < 16; ++qi) {
      const int qg = qbase + qi;
      float s_acc = 0.f;
#pragma unroll 8
      for (int d = 0; d < HD; ++d)
        s_acc += bf2f(q_sh[wave * 16 + qi][d]) * bf2f(k_sh[d][lane]);
      float sc = s_acc * scale;
      const int kg = t * KTILE + lane;
      if (kg > qg) sc = -INFINITY;                 // causal mask
      float mt = sc;
#pragma unroll
      for (int off = 32; off; off >>= 1) mt = fmaxf(mt, __shfl_xor(mt, off));
      const float mnew  = fmaxf(m_i[qi], mt);
      const float alpha = __expf(m_i[qi] - mnew);  // exp(-inf)=0 first time
      const float p     = __expf(sc - mnew);
      float ps = p;
#pragma unroll
      for (int off = 32; off; off >>= 1) ps += __shfl_xor(ps, off);
      m_i[qi] = mnew;
      l_i[qi] = l_i[qi] * alpha + ps;
      float a0 = 0.f, a1 = 0.f;
#pragma unroll 8
      for (int jj = 0; jj < KTILE; ++jj) {
        const float pj = __shfl(p, jj);            // cross-lane broadcast
        a0 += pj * bf2f(v_sh[jj][lane]);
        a1 += pj * bf2f(v_sh[jj][lane + 64]);
      }
      o0[qi] = o0[qi] * alpha + a0;
      o1[qi] = o1[qi] * alpha + a1;
    }
  }

  // epilogue: Y[b][q][h*HD + d]
#pragma unroll
  for (int qi = 0; qi < 16; ++qi) {
    const int qg = qbase + qi;
    const float invl = 1.f / l_i[qi];
    const size_t off = ((size_t)b * SEQ + qg) * EMB + h * HD;
    Y[off + lane]      = f2bf(o0[qi] * invl);
    Y[off + lane + 64] = f2bf(o1[qi] * invl);
  }
}

// ---------------------------------------------------------------------------
extern "C" void kernel_launch(void* const* d_in, const int* in_sizes, int n_in,
                              void* d_out, int out_size, void* d_ws, size_t ws_size,
                              hipStream_t stream) {
  // Inputs fp32 (reference dtype); OUTPUT fp32 (reference output dtype —
  // "else float*": the jnp.float32 reference returns float32).
  const float* x_f     = (const float*)d_in[0];   // [B,S,E]   fp32
  const float* w_qkv_f = (const float*)d_in[1];   // [3E,E]    fp32
  const float* w_out_f = (const float*)d_in[2];   // [E,E]     fp32
  float* out = (float*)d_out;                     // [B,S,E]   fp32

  const int M = BATCH * SEQ;                      // 4096
  const size_t n_x    = (size_t)M * EMB;          //  8,388,608
  const size_t n_wqkv = (size_t)3 * EMB * EMB;    // 12,582,912
  const size_t n_wout = (size_t)EMB * EMB;        //  4,194,304

  // Workspace layout (88 MB peak):
  //   [ xb 16MB ][ wqkvb 24MB ][ qkv 48MB ]
  u16* xb    = (u16*)d_ws;                        // 16 MB, dead after gemm1
  u16* wqkvb = xb + n_x;                          // 24 MB, dead after gemm1
  u16* qkv   = wqkvb + n_wqkv;                    // 48 MB [M, 3E], rope in-place
  u16* woutb = wqkvb;                             // reuse (8 MB of 24)
  u16* Yb    = xb;                                // reuse (exactly 16 MB)

  cvt_f32_bf16<<<(int)((n_x / 4 + 255) / 256), 256, 0, stream>>>(x_f, xb, (int)(n_x / 4));
  cvt_f32_bf16<<<(int)((n_wqkv / 4 + 255) / 256), 256, 0, stream>>>(w_qkv_f, wqkvb, (int)(n_wqkv / 4));

  gemm_bt<false><<<dim3(3 * EMB / BN, M / BM), 256, 0, stream>>>(
      xb, wqkvb, qkv, nullptr, M, 3 * EMB, EMB);

  rope_inplace<<<(BATCH * SEQ * NH * 64) / 256, 256, 0, stream>>>(qkv);

  cvt_f32_bf16<<<(int)((n_wout / 4 + 255) / 256), 256, 0, stream>>>(w_out_f, woutb, (int)(n_wout / 4));

  attn_flash<<<dim3(SEQ / QB, BATCH * NH), 256, 0, stream>>>(qkv, Yb);

  gemm_bt<true><<<dim3(EMB / BN, M / BM), 256, 0, stream>>>(
      Yb, woutb, nullptr, out, M, EMB, EMB);
}

// Round 7
// 537.331 us; speedup vs baseline: 8.7948x; 8.7948x over previous
//
#include <hip/hip_runtime.h>
#include <stdint.h>

// Problem constants (reference: B=2, S=2048, E=2048, H=16, D=128)
constexpr int BATCH = 2;
constexpr int SEQ   = 2048;
constexpr int EMB   = 2048;
constexpr int NH    = 16;
constexpr int HD    = 128;
constexpr int QKV3  = 3 * EMB;

typedef unsigned short u16;
typedef __attribute__((ext_vector_type(8))) short bf16x8;
typedef __attribute__((ext_vector_type(4))) float floatx4;

__device__ inline float bf2f(u16 u) {
  union { unsigned int i; float f; } v; v.i = ((unsigned int)u) << 16; return v.f;
}
__device__ inline u16 f2bf(float f) {
  union { float f; unsigned int i; } v; v.f = f;
  unsigned int x = v.i;
  return (u16)((x + 0x7fffu + ((x >> 16) & 1u)) >> 16);  // RNE
}

__device__ inline void load_lds16(const void* g, void* l) {
  __builtin_amdgcn_global_load_lds((const __attribute__((address_space(1))) unsigned int*)g,
                                   (__attribute__((address_space(3))) unsigned int*)l,
                                   16, 0, 0);
}

// ---------------------------------------------------------------------------
// fp32 -> bf16 elementwise convert (vectorized x4)
// ---------------------------------------------------------------------------
__global__ void cvt_f32_bf16(const float* __restrict__ src, u16* __restrict__ dst, int n4) {
  const int i = blockIdx.x * blockDim.x + threadIdx.x;
  if (i < n4) {
    const float4 v = ((const float4*)src)[i];
    ushort4 o;
    o.x = f2bf(v.x); o.y = f2bf(v.y); o.z = f2bf(v.z); o.w = f2bf(v.w);
    ((ushort4*)dst)[i] = o;
  }
}

// ---------------------------------------------------------------------------
// C[M,N] = A[M,K] @ B[N,K]^T   (bf16 in, fp32 accumulate) — m97 pattern
// ---------------------------------------------------------------------------
constexpr int BM = 128, BN = 128, BK = 32;

template <bool F32OUT>
__global__ __launch_bounds__(256) void gemm_bt(const u16* __restrict__ A,
                                               const u16* __restrict__ Bm,
                                               u16* __restrict__ Cb,
                                               float* __restrict__ Cf,
                                               int M, int N, int K) {
  __shared__ __align__(16) u16 As[BM * BK];
  __shared__ __align__(16) u16 Bs[BN * BK];
  const int tid  = threadIdx.x;
  const int wave = tid >> 6, lane = tid & 63;
  const int wm = (wave & 1) * 64, wn = (wave >> 1) * 64;
  const int m0 = blockIdx.y * BM, n0 = blockIdx.x * BN;

  floatx4 acc[4][4];
#pragma unroll
  for (int i = 0; i < 4; ++i)
#pragma unroll
    for (int j = 0; j < 4; ++j) acc[i][j] = {0.f, 0.f, 0.f, 0.f};

  const int lrow = lane >> 2;
  const int lcol = (lane & 3) * 8;
  const int frow = lane & 15;
  const int fk   = (lane >> 4) * 8;

  for (int kt = 0; kt < K; kt += BK) {
#pragma unroll
    for (int inst = 0; inst < 2; ++inst) {
      const int rbase = wave * 32 + inst * 16;
      load_lds16(A  + (size_t)(m0 + rbase + lrow) * K + kt + lcol, &As[rbase * BK]);
      load_lds16(Bm + (size_t)(n0 + rbase + lrow) * K + kt + lcol, &Bs[rbase * BK]);
    }
    asm volatile("s_waitcnt vmcnt(0)" ::: "memory");
    __syncthreads();

    bf16x8 af[4], bfr[4];
#pragma unroll
    for (int mi = 0; mi < 4; ++mi)
      af[mi] = *(const bf16x8*)&As[(wm + mi * 16 + frow) * BK + fk];
#pragma unroll
    for (int ni = 0; ni < 4; ++ni)
      bfr[ni] = *(const bf16x8*)&Bs[(wn + ni * 16 + frow) * BK + fk];
#pragma unroll
    for (int mi = 0; mi < 4; ++mi)
#pragma unroll
      for (int ni = 0; ni < 4; ++ni)
        acc[mi][ni] = __builtin_amdgcn_mfma_f32_16x16x32_bf16(af[mi], bfr[ni], acc[mi][ni], 0, 0, 0);
    __syncthreads();
  }

  const int crow0 = (lane >> 4) * 4;
  const int ccol  = lane & 15;
#pragma unroll
  for (int mi = 0; mi < 4; ++mi)
#pragma unroll
    for (int ni = 0; ni < 4; ++ni) {
      const int row = m0 + wm + mi * 16 + crow0;
      const int col = n0 + wn + ni * 16 + ccol;
#pragma unroll
      for (int r = 0; r < 4; ++r) {
        const size_t off = (size_t)(row + r) * N + col;
        if (F32OUT) Cf[off] = acc[mi][ni][r];
        else        Cb[off] = f2bf(acc[mi][ni][r]);
      }
    }
}

// ---------------------------------------------------------------------------
// In-place RoPE on qkv[B,S,3,NH,HD]: rotates Q and K thirds, V untouched.
// ---------------------------------------------------------------------------
__global__ void rope_inplace(u16* __restrict__ qkv) {
  const int t   = blockIdx.x * blockDim.x + threadIdx.x;
  const int j   = t & 63;
  const int idx = t >> 6;
  const int h   = idx & (NH - 1);
  const int bs  = idx >> 4;
  const int s   = bs & (SEQ - 1);

  u16* base = qkv + (size_t)bs * QKV3 + h * HD;

  const float inv_freq = exp2f(-(float)j * (13.287712379549449f / 64.0f)); // 10000^(-j/64)
  const float ang = (float)s * inv_freq;
  const float c = cosf(ang), sn = sinf(ang);

#pragma unroll
  for (int part = 0; part < 2; ++part) {
    u16* p = base + part * EMB;
    const float x1 = bf2f(p[j]), x2 = bf2f(p[j + 64]);
    p[j]      = f2bf(x1 * c - x2 * sn);
    p[j + 64] = f2bf(x2 * c + x1 * sn);
  }
}

// ---------------------------------------------------------------------------
// V transpose: qkv V-third [b][s][h][d] -> Vt[bh][d][s]  (key-contiguous rows)
// block 256, grid (SEQ/64, B*NH). LDS tile transpose.
// ---------------------------------------------------------------------------
__global__ __launch_bounds__(256) void transpose_v(const u16* __restrict__ qkv,
                                                   u16* __restrict__ VT) {
  __shared__ u16 vtile[64][136];   // padded
  const int tid = threadIdx.x;
  const int s0 = blockIdx.x * 64;
  const int bh = blockIdx.y;
  const int b = bh >> 4, h = bh & 15;

  const u16* Vp = qkv + (size_t)b * SEQ * QKV3 + 2 * EMB + h * HD;
  {
    const int r = tid >> 2, cp = (tid & 3) * 32;
    const uint4* src = (const uint4*)(Vp + (size_t)(s0 + r) * QKV3 + cp);
    uint4* dst = (uint4*)&vtile[r][cp];
    dst[0] = src[0]; dst[1] = src[1]; dst[2] = src[2]; dst[3] = src[3];
  }
  __syncthreads();
  {
    const int d = tid >> 1, ck = (tid & 1) * 32;
    ushort4 o[8];
#pragma unroll
    for (int i = 0; i < 8; ++i) {
      o[i].x = vtile[ck + i * 4 + 0][d];
      o[i].y = vtile[ck + i * 4 + 1][d];
      o[i].z = vtile[ck + i * 4 + 2][d];
      o[i].w = vtile[ck + i * 4 + 3][d];
    }
    ushort4* dst = (ushort4*)(VT + ((size_t)bh * HD + d) * SEQ + s0 + ck);
#pragma unroll
    for (int i = 0; i < 8; ++i) dst[i] = o[i];
  }
}

// ---------------------------------------------------------------------------
// MFMA flash attention (online softmax), causal.
// block = 256 (4 waves); 64 queries/block (16/wave); key tiles of 64.
// QK^T and PV on mfma_f32_16x16x32_bf16. P transits LDS (m120 pattern).
// ---------------------------------------------------------------------------
constexpr int QSTR = 136;   // q_sh/k_sh row stride (pad: breaks 128-elem bank alias)
constexpr int VSTR = 72;    // vt_sh row stride (144B, 16B-aligned)
constexpr int PSTR = 72;    // p_sh row stride

__global__ __launch_bounds__(256) void attn_mfma(const u16* __restrict__ qkv,
                                                 const u16* __restrict__ VT,
                                                 u16* __restrict__ Y) {
  __shared__ __align__(16) u16 q_sh[64][QSTR];    // 17 KB
  __shared__ __align__(16) u16 k_sh[64][QSTR];    // 17 KB
  __shared__ __align__(16) u16 vt_sh[HD][VSTR];   // 18 KB
  __shared__ __align__(16) u16 p_sh[4][16][PSTR]; //  9 KB

  const int tid  = threadIdx.x;
  const int wave = tid >> 6, lane = tid & 63;
  const int bh = blockIdx.y;
  const int q0 = blockIdx.x * 64;
  const int b = bh >> 4, h = bh & 15;

  const u16* Qp  = qkv + (size_t)b * SEQ * QKV3 + h * HD;
  const u16* Kp  = Qp + EMB;
  const u16* VTp = VT + (size_t)bh * HD * SEQ;

  { // stage Q once: 64 rows x 128
    const int r = tid >> 2, cp = (tid & 3) * 32;
    const uint4* src = (const uint4*)(Qp + (size_t)(q0 + r) * QKV3 + cp);
    uint4* dst = (uint4*)&q_sh[r][cp];
    dst[0] = src[0]; dst[1] = src[1]; dst[2] = src[2]; dst[3] = src[3];
  }

  const int frow = lane & 15;
  const int quad = lane >> 4;
  const int fk   = quad * 8;
  const int qbase = q0 + wave * 16;

  floatx4 o_acc[8];
#pragma unroll
  for (int dt = 0; dt < 8; ++dt) o_acc[dt] = {0.f, 0.f, 0.f, 0.f};
  float m_r[4], l_r[4];
#pragma unroll
  for (int r = 0; r < 4; ++r) { m_r[r] = -INFINITY; l_r[r] = 0.f; }

  const int ntiles = q0 / 64 + 1;
  const float scale = 0.08838834764831845f;   // 1/sqrt(128)

  for (int t = 0; t < ntiles; ++t) {
    __syncthreads();   // prior-tile readers done
    { // stage K tile (64 keys x 128d)
      const int r = tid >> 2, cp = (tid & 3) * 32;
      const uint4* src = (const uint4*)(Kp + (size_t)(t * 64 + r) * QKV3 + cp);
      uint4* dst = (uint4*)&k_sh[r][cp];
      dst[0] = src[0]; dst[1] = src[1]; dst[2] = src[2]; dst[3] = src[3];
      // stage Vt tile (128d x 64 keys), key-contiguous rows
      const int d = tid >> 1, ck = (tid & 1) * 32;
      const uint4* sv = (const uint4*)(VTp + (size_t)d * SEQ + t * 64 + ck);
      uint4* dv = (uint4*)&vt_sh[d][ck];
      dv[0] = sv[0]; dv[1] = sv[1]; dv[2] = sv[2]; dv[3] = sv[3];
    }
    __syncthreads();

    // ---- S = Q K^T for this wave's 16 queries x 64 keys
    bf16x8 aq[4];
#pragma unroll
    for (int ks = 0; ks < 4; ++ks)
      aq[ks] = *(const bf16x8*)&q_sh[wave * 16 + frow][ks * 32 + fk];

    floatx4 s4[4];
#pragma unroll
    for (int nt = 0; nt < 4; ++nt) {
      floatx4 acc = {0.f, 0.f, 0.f, 0.f};
#pragma unroll
      for (int ks = 0; ks < 4; ++ks) {
        const bf16x8 bk = *(const bf16x8*)&k_sh[nt * 16 + frow][ks * 32 + fk];
        acc = __builtin_amdgcn_mfma_f32_16x16x32_bf16(aq[ks], bk, acc, 0, 0, 0);
      }
      s4[nt] = acc;
    }

    // scale + causal mask (only the diagonal tile needs it)
#pragma unroll
    for (int nt = 0; nt < 4; ++nt)
#pragma unroll
      for (int r = 0; r < 4; ++r) {
        float sv = s4[nt][r] * scale;
        if (t == ntiles - 1) {
          const int key = t * 64 + nt * 16 + frow;   // C col = lane&15
          const int qg  = qbase + quad * 4 + r;      // C row
          if (key > qg) sv = -INFINITY;
        }
        s4[nt][r] = sv;
      }

    // row max (cols live in the low-4 lane bits)
    float mt[4];
#pragma unroll
    for (int r = 0; r < 4; ++r)
      mt[r] = fmaxf(fmaxf(s4[0][r], s4[1][r]), fmaxf(s4[2][r], s4[3][r]));
#pragma unroll
    for (int off = 1; off <= 8; off <<= 1)
#pragma unroll
      for (int r = 0; r < 4; ++r) mt[r] = fmaxf(mt[r], __shfl_xor(mt[r], off));

    float alpha[4], mnew[4];
#pragma unroll
    for (int r = 0; r < 4; ++r) {
      mnew[r]  = fmaxf(m_r[r], mt[r]);
      alpha[r] = __expf(m_r[r] - mnew[r]);   // exp(-inf)=0 first time
      m_r[r]   = mnew[r];
    }

    // p = exp(s - mnew), row sums
    float rs[4] = {0.f, 0.f, 0.f, 0.f};
#pragma unroll
    for (int nt = 0; nt < 4; ++nt)
#pragma unroll
      for (int r = 0; r < 4; ++r) {
        const float p = __expf(s4[nt][r] - mnew[r]);
        s4[nt][r] = p;
        rs[r] += p;
      }
#pragma unroll
    for (int off = 1; off <= 8; off <<= 1)
#pragma unroll
      for (int r = 0; r < 4; ++r) rs[r] += __shfl_xor(rs[r], off);
#pragma unroll
    for (int r = 0; r < 4; ++r) l_r[r] = l_r[r] * alpha[r] + rs[r];

    // rescale O
#pragma unroll
    for (int dt = 0; dt < 8; ++dt)
#pragma unroll
      for (int r = 0; r < 4; ++r) o_acc[dt][r] *= alpha[r];

    // P -> LDS (C-layout scatter; same-wave DS ordering guarantees RAW)
#pragma unroll
    for (int nt = 0; nt < 4; ++nt)
#pragma unroll
      for (int r = 0; r < 4; ++r)
        p_sh[wave][quad * 4 + r][nt * 16 + frow] = f2bf(s4[nt][r]);

    // ---- O += P V  (A = P from LDS in A-layout, B = Vt key-contiguous)
#pragma unroll
    for (int step = 0; step < 2; ++step) {
      const bf16x8 ap = *(const bf16x8*)&p_sh[wave][frow][step * 32 + fk];
#pragma unroll
      for (int dt = 0; dt < 8; ++dt) {
        const bf16x8 bv = *(const bf16x8*)&vt_sh[dt * 16 + frow][step * 32 + fk];
        o_acc[dt] = __builtin_amdgcn_mfma_f32_16x16x32_bf16(ap, bv, o_acc[dt], 0, 0, 0);
      }
    }
  }

  // epilogue: Y[b][q][h*HD + d], C-layout regs
  float invl[4];
#pragma unroll
  for (int r = 0; r < 4; ++r) invl[r] = 1.f / l_r[r];
#pragma unroll
  for (int dt = 0; dt < 8; ++dt)
#pragma unroll
    for (int r = 0; r < 4; ++r) {
      const int qg = qbase + quad * 4 + r;
      const size_t off = ((size_t)b * SEQ + qg) * EMB + h * HD + dt * 16 + frow;
      Y[off] = f2bf(o_acc[dt][r] * invl[r]);
    }
}

// ---------------------------------------------------------------------------
extern "C" void kernel_launch(void* const* d_in, const int* in_sizes, int n_in,
                              void* d_out, int out_size, void* d_ws, size_t ws_size,
                              hipStream_t stream) {
  const float* x_f     = (const float*)d_in[0];   // [B,S,E]   fp32
  const float* w_qkv_f = (const float*)d_in[1];   // [3E,E]    fp32
  const float* w_out_f = (const float*)d_in[2];   // [E,E]     fp32
  float* out = (float*)d_out;                     // [B,S,E]   fp32

  const int M = BATCH * SEQ;                      // 4096
  const size_t n_x    = (size_t)M * EMB;
  const size_t n_wqkv = (size_t)3 * EMB * EMB;
  const size_t n_wout = (size_t)EMB * EMB;

  // Workspace (104 MB): [ xb 16MB ][ wqkvb 24MB ][ qkv 48MB ][ VT 16MB ]
  u16* xb    = (u16*)d_ws;
  u16* wqkvb = xb + n_x;
  u16* qkv   = wqkvb + n_wqkv;
  u16* VT    = qkv + (size_t)M * QKV3;
  u16* woutb = wqkvb;                             // reuse after gemm1
  u16* Yb    = xb;                                // reuse after gemm1

  cvt_f32_bf16<<<(int)((n_x / 4 + 255) / 256), 256, 0, stream>>>(x_f, xb, (int)(n_x / 4));
  cvt_f32_bf16<<<(int)((n_wqkv / 4 + 255) / 256), 256, 0, stream>>>(w_qkv_f, wqkvb, (int)(n_wqkv / 4));

  gemm_bt<false><<<dim3(QKV3 / BN, M / BM), 256, 0, stream>>>(
      xb, wqkvb, qkv, nullptr, M, QKV3, EMB);

  rope_inplace<<<(BATCH * SEQ * NH * 64) / 256, 256, 0, stream>>>(qkv);
  transpose_v<<<dim3(SEQ / 64, BATCH * NH), 256, 0, stream>>>(qkv, VT);

  cvt_f32_bf16<<<(int)((n_wout / 4 + 255) / 256), 256, 0, stream>>>(w_out_f, woutb, (int)(n_wout / 4));

  attn_mfma<<<dim3(SEQ / 64, BATCH * NH), 256, 0, stream>>>(qkv, VT, Yb);

  gemm_bt<true><<<dim3(EMB / BN, M / BM), 256, 0, stream>>>(
      Yb, woutb, nullptr, out, M, EMB, EMB);
}